// Round 19
// baseline (125.309 us; speedup 1.0000x reference)
//
#include <hip/hip_runtime.h>
#include <math.h>

#define N 8192
#define D 512
#define TT 64              // 8192/128 tiles per side
#define NT 2080            // TT*(TT+1)/2
#define NEG_INF_SENT (-3.0e38f)
#define SCALE1 0x7F7F7F7F   // E8M0 = 127 -> 2^0 = 1.0 in all four bytes
#define FMT_FP4 4           // cbsz/blgp format code for fp4 (e2m1)

typedef __attribute__((ext_vector_type(8))) int int8x;      // operand regs (fp4 uses low 4)
typedef __attribute__((ext_vector_type(16))) float f32x16;  // 32x32 C/D frag

__device__ inline void lse_merge(float& m1, float& s1, float m2, float s2) {
    float M = fmaxf(m1, m2);
    s1 = s1 * __expf(m1 - M) + s2 * __expf(m2 - M);
    m1 = M;
}

__device__ inline unsigned fp4_nib(float v) {
    // e2m1 nearest: values 0,.5,1,1.5,2,3,4,6 (sign bit 3)
    unsigned s = (__float_as_uint(v) >> 28) & 8u;
    float av = fabsf(v);
    unsigned c;
    if (av < 1.25f)      c = (av < 0.25f) ? 0u : (av < 0.75f) ? 1u : 2u;
    else if (av < 2.5f)  c = (av < 1.75f) ? 3u : 4u;
    else                 c = (av < 3.5f) ? 5u : (av < 5.0f) ? 6u : 7u;
    return s | c;
}

// ---- fused cast(fp32->fp4 e2m1, fragment-swizzled layout) + row-sumsq --------
// Also zeroes the last-block ticket (d_ws is re-poisoned 0xAA before every
// launch; cast runs stream-ordered before pair, so the ticket is always 0
// when pair starts). xb layout: 32-row group g, K-chunk c: 1-KB unit at
// ((g*8+c)<<10), interior = lane*16 image of the MFMA operand
// (lane l: row l&31, k=(l>>5)*32+[0,32)). Nibbles k-ascending, low first.
__global__ __launch_bounds__(256) void cast_rowsq_kernel(const float* __restrict__ x,
                                                         unsigned char* __restrict__ xb,
                                                         float* __restrict__ sq,
                                                         unsigned* __restrict__ ticket) {
    if (blockIdx.x == 0 && threadIdx.x == 0) *ticket = 0u;
#pragma unroll
    for (int g4 = 0; g4 < 4; ++g4) {
        int row = blockIdx.x * 16 + g4 * 4 + (threadIdx.x >> 6);
        int lane = threadIdx.x & 63;
        const float4* xr = (const float4*)(x + (size_t)row * D);
        float4 a = xr[lane * 2], b = xr[lane * 2 + 1];
        float v[8] = {a.x, a.y, a.z, a.w, b.x, b.y, b.z, b.w};
        float s = 0.f;
        unsigned pk = 0;
#pragma unroll
        for (int e = 0; e < 8; ++e) {
            s += v[e] * v[e];
            pk |= fp4_nib(v[e]) << (4 * e);
        }
        int g = row >> 5, rl = row & 31;
        int k0 = lane * 8;
        int c = k0 >> 6;                   // K-chunk
        int seg = (k0 >> 5) & 1;           // 32-k segment
        int bb = (k0 & 31) >> 1;           // byte within 16-B row-seg
        size_t addr = ((size_t)(g * 8 + c) << 10) + ((seg * 32 + rl) << 4) + bb;
        *(unsigned*)(xb + addr) = pk;
#pragma unroll
        for (int off = 32; off > 0; off >>= 1) s += __shfl_down(s, off, 64);
        if (lane == 0) sq[row] = s;
    }
}

// ---- LDS-free MX-fp4 MFMA pair kernel + fused last-block finalize ------------
// 128x128 tile, 4 waves, wave-tile 64x64 = 2x2 frags of 32x32x64 (acc 64 AGPR).
// r16 K-loop (best measured): K-chunk 64, register ping-pong, dense 1-KB
// fragment loads, no LDS / no K-loop barriers. Tail: device-scope ticket;
// the last block re-reduces all 2080 (bm,bs) and writes out[0] -- removes the
// finalize launch from the graph.
// C/D layout (m74/m101): col=lane&31, row=(reg&3)+8*(reg>>2)+4*(lane>>5).
__global__ __launch_bounds__(256, 2) void pair_mfma_kernel(const unsigned char* __restrict__ xb,
                                                           const float* __restrict__ sq,
                                                           float* __restrict__ bm,
                                                           float* __restrict__ bs,
                                                           unsigned* __restrict__ ticket,
                                                           float* __restrict__ out) {
    const int p = blockIdx.x;
    const int b = (p & 7) * 260 + (p >> 3);          // XCD-contiguous runs (2080 = 8*260)
    int bi = 0;
    while ((bi + 1) * (2 * TT - bi) / 2 <= b) ++bi;
    const int bj = bi + (b - bi * (2 * TT - bi + 1) / 2);
    const int i0 = bi * 128, j0 = bj * 128;
    const int gA = i0 >> 5, gB = j0 >> 5;

    const int tid = threadIdx.x;
    const int lane = tid & 63;
    const int w = tid >> 6;          // 0..3
    const int wy = w >> 1, wx = w & 1;
    const int l31 = lane & 31;
    const int l5 = lane >> 5;

    int aOff[2], bOff[2];
#pragma unroll
    for (int mi = 0; mi < 2; ++mi) {
        aOff[mi] = (((gA + 2 * wy + mi) * 8) << 10) + (lane << 4);
        bOff[mi] = (((gB + 2 * wx + mi) * 8) << 10) + (lane << 4);
    }

    f32x16 acc[2][2];
#pragma unroll
    for (int mi = 0; mi < 2; ++mi)
#pragma unroll
        for (int ni = 0; ni < 2; ++ni)
#pragma unroll
            for (int r = 0; r < 16; ++r) acc[mi][ni][r] = 0.f;

    int8x af[2][2], bf[2][2];    // [buf][frag]; fp4 uses regs 0..3, 4..7 stay 0
#pragma unroll
    for (int buf = 0; buf < 2; ++buf)
#pragma unroll
        for (int mi = 0; mi < 2; ++mi)
#pragma unroll
            for (int r = 0; r < 8; ++r) { af[buf][mi][r] = 0; bf[buf][mi][r] = 0; }

    auto load_chunk = [&](int c, int buf) {
        const int co = c << 10;
#pragma unroll
        for (int mi = 0; mi < 2; ++mi) {
            uint4 av = *(const uint4*)(xb + aOff[mi] + co);
            uint4 bv = *(const uint4*)(xb + bOff[mi] + co);
            af[buf][mi][0] = av.x; af[buf][mi][1] = av.y;
            af[buf][mi][2] = av.z; af[buf][mi][3] = av.w;
            bf[buf][mi][0] = bv.x; bf[buf][mi][1] = bv.y;
            bf[buf][mi][2] = bv.z; bf[buf][mi][3] = bv.w;
        }
    };

    load_chunk(0, 0);
#pragma unroll
    for (int c = 0; c < 8; ++c) {          // 8 K-chunks of 64, ping-pong buffers
        const int cur = c & 1;
        if (c < 7) load_chunk(c + 1, cur ^ 1);
#pragma unroll
        for (int mi = 0; mi < 2; ++mi)
#pragma unroll
            for (int ni = 0; ni < 2; ++ni)
                acc[mi][ni] = __builtin_amdgcn_mfma_scale_f32_32x32x64_f8f6f4(
                    af[cur][mi], bf[cur][ni], acc[mi][ni],
                    FMT_FP4, FMT_FP4, 0, SCALE1, 0, SCALE1);
    }

    // ---- branch-free epilogue ------------------------------------------------
    const bool offdiag = (bi != bj);
    float sqj[2];
#pragma unroll
    for (int ni = 0; ni < 2; ++ni) sqj[ni] = sq[j0 + wx * 64 + ni * 32 + l31];

    float m = NEG_INF_SENT;
#pragma unroll
    for (int mi = 0; mi < 2; ++mi) {
#pragma unroll
        for (int r = 0; r < 16; ++r) {
            int row32 = (r & 3) + 8 * (r >> 2) + 4 * l5;
            int i = i0 + wy * 64 + mi * 32 + row32;
            float sqi = sq[i];
#pragma unroll
            for (int ni = 0; ni < 2; ++ni) {
                int j = j0 + wx * 64 + ni * 32 + l31;
                float d2 = fmaxf(sqi + sqj[ni] - 2.f * acc[mi][ni][r], 0.f);
                float tv = (offdiag || j > i) ? (-2.0f * d2) : NEG_INF_SENT;
                acc[mi][ni][r] = tv;
                m = fmaxf(m, tv);
            }
        }
    }
    float s = 0.f;
#pragma unroll
    for (int mi = 0; mi < 2; ++mi)
#pragma unroll
        for (int ni = 0; ni < 2; ++ni)
#pragma unroll
            for (int r = 0; r < 16; ++r)
                s += __expf(acc[mi][ni][r] - m);

#pragma unroll
    for (int off = 32; off > 0; off >>= 1) {
        float m2 = __shfl_down(m, off, 64);
        float s2 = __shfl_down(s, off, 64);
        lse_merge(m, s, m2, s2);
    }
    __shared__ float rm[4], rs[4];
    __shared__ int is_last;
    if (lane == 0) { rm[w] = m; rs[w] = s; }
    __syncthreads();
    if (tid == 0) {
#pragma unroll
        for (int v = 1; v < 4; ++v) lse_merge(rm[0], rs[0], rm[v], rs[v]);
        bm[p] = rm[0];
        bs[p] = rs[0];
        __threadfence();                          // release per-block result
        unsigned old = atomicAdd(ticket, 1u);     // device-scope
        is_last = (old == NT - 1u);
    }
    __syncthreads();

    // ---- fused finalize: only the last block to arrive -----------------------
    if (is_last) {
        __threadfence();                          // acquire all bm/bs
        float fm = NEG_INF_SENT, fs = 0.f;
        for (int t = tid; t < NT; t += 256) lse_merge(fm, fs, bm[t], bs[t]);
#pragma unroll
        for (int off = 32; off > 0; off >>= 1) {
            float m2 = __shfl_down(fm, off, 64);
            float s2 = __shfl_down(fs, off, 64);
            lse_merge(fm, fs, m2, s2);
        }
        __shared__ float gm[4], gs[4];
        if (lane == 0) { gm[w] = fm; gs[w] = fs; }
        __syncthreads();
        if (tid == 0) {
#pragma unroll
            for (int v = 1; v < 4; ++v) lse_merge(gm[0], gs[0], gm[v], gs[v]);
            const float log_num_pairs = 17.3285362f;  // log(8192*8191/2)
            out[0] = gm[0] + logf(gs[0]) - log_num_pairs;
        }
    }
}

extern "C" void kernel_launch(void* const* d_in, const int* in_sizes, int n_in,
                              void* d_out, int out_size, void* d_ws, size_t ws_size,
                              hipStream_t stream) {
    const float* x = (const float*)d_in[0];
    float* out = (float*)d_out;

    const size_t xb_bytes = (size_t)N * D / 2;   // 2 MB fp4 (swizzled)
    unsigned char* xb = (unsigned char*)d_ws;
    float* sq = (float*)((char*)d_ws + xb_bytes);
    float* bm = sq + N;
    float* bs = bm + NT;
    unsigned* ticket = (unsigned*)(bs + NT);

    cast_rowsq_kernel<<<N / 16, 256, 0, stream>>>(x, xb, sq, ticket);
    pair_mfma_kernel<<<NT, 256, 0, stream>>>(xb, sq, bm, bs, ticket, out);
}

// Round 20
// 89.759 us; speedup vs baseline: 1.3961x; 1.3961x over previous
//
#include <hip/hip_runtime.h>
#include <math.h>

#define N 8192
#define D 512
#define TT 64              // 8192/128 tiles per side
#define NT 2080            // TT*(TT+1)/2
#define NEG_INF_SENT (-3.0e38f)
#define SCALE1 0x7F7F7F7F   // E8M0 = 127 -> 2^0 = 1.0 in all four bytes
#define FMT_FP4 4           // cbsz/blgp format code for fp4 (e2m1)

typedef __attribute__((ext_vector_type(8))) int int8x;      // operand regs (fp4 uses low 4)
typedef __attribute__((ext_vector_type(16))) float f32x16;  // 32x32 C/D frag

__device__ inline void lse_merge(float& m1, float& s1, float m2, float s2) {
    float M = fmaxf(m1, m2);
    s1 = s1 * __expf(m1 - M) + s2 * __expf(m2 - M);
    m1 = M;
}

__device__ inline unsigned fp4_nib(float v) {
    // e2m1 nearest: values 0,.5,1,1.5,2,3,4,6 (sign bit 3)
    unsigned s = (__float_as_uint(v) >> 28) & 8u;
    float av = fabsf(v);
    unsigned c;
    if (av < 1.25f)      c = (av < 0.25f) ? 0u : (av < 0.75f) ? 1u : 2u;
    else if (av < 2.5f)  c = (av < 1.75f) ? 3u : 4u;
    else                 c = (av < 3.5f) ? 5u : (av < 5.0f) ? 6u : 7u;
    return s | c;
}

// ---- fused cast(fp32->fp4 e2m1, fragment-swizzled layout) + row-sumsq --------
// xb layout: 32-row group g (0..255), K-chunk c (64 k, 0..7): one 1-KB unit at
// ((g*8+c)<<10); interior offset = ((kseg32*32 + row&31)<<4) + (k&31)/2  ==
// lane*16 for the MFMA operand read (lane l: row l&31, k=(l>>5)*32+[0,32)).
// Nibble order: k ascending, low nibble first.
__global__ __launch_bounds__(256) void cast_rowsq_kernel(const float* __restrict__ x,
                                                         unsigned char* __restrict__ xb,
                                                         float* __restrict__ sq) {
#pragma unroll
    for (int g4 = 0; g4 < 4; ++g4) {
        int row = blockIdx.x * 16 + g4 * 4 + (threadIdx.x >> 6);
        int lane = threadIdx.x & 63;
        const float4* xr = (const float4*)(x + (size_t)row * D);
        float4 a = xr[lane * 2], b = xr[lane * 2 + 1];
        float v[8] = {a.x, a.y, a.z, a.w, b.x, b.y, b.z, b.w};
        float s = 0.f;
        unsigned pk = 0;
#pragma unroll
        for (int e = 0; e < 8; ++e) {
            s += v[e] * v[e];
            pk |= fp4_nib(v[e]) << (4 * e);
        }
        int g = row >> 5, rl = row & 31;
        int k0 = lane * 8;
        int c = k0 >> 6;                   // K-chunk
        int seg = (k0 >> 5) & 1;           // 32-k segment
        int bb = (k0 & 31) >> 1;           // byte within 16-B row-seg: 0,4,8,12
        size_t addr = ((size_t)(g * 8 + c) << 10) + ((seg * 32 + rl) << 4) + bb;
        *(unsigned*)(xb + addr) = pk;
#pragma unroll
        for (int off = 32; off > 0; off >>= 1) s += __shfl_down(s, off, 64);
        if (lane == 0) sq[row] = s;
    }
}

// ---- LDS-free MX-fp4 MFMA pair kernel (r16 configuration, best measured) -----
// 128x128 tile, 4 waves, wave-tile 64x64 = 2x2 frags of 32x32x64 (acc 64 AGPR).
// K-chunk 64, register ping-pong, 4 dense 1-KB fragment loads per chunk (one
// dwordx4/lane), no LDS, no K-loop barriers, launch_bounds(256,2).
// NOTE: keep this kernel free of extra control flow / atomics -- r19's fused
// tail dropped the allocator to 60 VGPRs and serialized the K-loop (65 us).
// C/D layout (m74/m101): col=lane&31, row=(reg&3)+8*(reg>>2)+4*(lane>>5).
__global__ __launch_bounds__(256, 2) void pair_mfma_kernel(const unsigned char* __restrict__ xb,
                                                           const float* __restrict__ sq,
                                                           float* __restrict__ bm,
                                                           float* __restrict__ bs) {
    const int p = blockIdx.x;
    const int b = (p & 7) * 260 + (p >> 3);          // XCD-contiguous runs (2080 = 8*260)
    int bi = 0;
    while ((bi + 1) * (2 * TT - bi) / 2 <= b) ++bi;
    const int bj = bi + (b - bi * (2 * TT - bi + 1) / 2);
    const int i0 = bi * 128, j0 = bj * 128;
    const int gA = i0 >> 5, gB = j0 >> 5;

    const int tid = threadIdx.x;
    const int lane = tid & 63;
    const int w = tid >> 6;          // 0..3
    const int wy = w >> 1, wx = w & 1;
    const int l31 = lane & 31;
    const int l5 = lane >> 5;

    // per-lane base offsets of this wave's 4 fragment unit-streams (chunk 0)
    int aOff[2], bOff[2];
#pragma unroll
    for (int mi = 0; mi < 2; ++mi) {
        aOff[mi] = (((gA + 2 * wy + mi) * 8) << 10) + (lane << 4);
        bOff[mi] = (((gB + 2 * wx + mi) * 8) << 10) + (lane << 4);
    }

    f32x16 acc[2][2];
#pragma unroll
    for (int mi = 0; mi < 2; ++mi)
#pragma unroll
        for (int ni = 0; ni < 2; ++ni)
#pragma unroll
            for (int r = 0; r < 16; ++r) acc[mi][ni][r] = 0.f;

    int8x af[2][2], bf[2][2];    // [buf][frag]; fp4 uses regs 0..3, 4..7 stay 0
#pragma unroll
    for (int buf = 0; buf < 2; ++buf)
#pragma unroll
        for (int mi = 0; mi < 2; ++mi)
#pragma unroll
            for (int r = 0; r < 8; ++r) { af[buf][mi][r] = 0; bf[buf][mi][r] = 0; }

    auto load_chunk = [&](int c, int buf) {
        const int co = c << 10;     // c*1024
#pragma unroll
        for (int mi = 0; mi < 2; ++mi) {
            uint4 av = *(const uint4*)(xb + aOff[mi] + co);
            uint4 bv = *(const uint4*)(xb + bOff[mi] + co);
            af[buf][mi][0] = av.x; af[buf][mi][1] = av.y;
            af[buf][mi][2] = av.z; af[buf][mi][3] = av.w;
            bf[buf][mi][0] = bv.x; bf[buf][mi][1] = bv.y;
            bf[buf][mi][2] = bv.z; bf[buf][mi][3] = bv.w;
        }
    };

    load_chunk(0, 0);
#pragma unroll
    for (int c = 0; c < 8; ++c) {          // 8 K-chunks of 64, ping-pong buffers
        const int cur = c & 1;
        if (c < 7) load_chunk(c + 1, cur ^ 1);
#pragma unroll
        for (int mi = 0; mi < 2; ++mi)
#pragma unroll
            for (int ni = 0; ni < 2; ++ni)
                acc[mi][ni] = __builtin_amdgcn_mfma_scale_f32_32x32x64_f8f6f4(
                    af[cur][mi], bf[cur][ni], acc[mi][ni],
                    FMT_FP4, FMT_FP4, 0, SCALE1, 0, SCALE1);
    }

    // ---- branch-free epilogue ------------------------------------------------
    const bool offdiag = (bi != bj);
    float sqj[2];
#pragma unroll
    for (int ni = 0; ni < 2; ++ni) sqj[ni] = sq[j0 + wx * 64 + ni * 32 + l31];

    float m = NEG_INF_SENT;
#pragma unroll
    for (int mi = 0; mi < 2; ++mi) {
#pragma unroll
        for (int r = 0; r < 16; ++r) {
            int row32 = (r & 3) + 8 * (r >> 2) + 4 * l5;
            int i = i0 + wy * 64 + mi * 32 + row32;
            float sqi = sq[i];
#pragma unroll
            for (int ni = 0; ni < 2; ++ni) {
                int j = j0 + wx * 64 + ni * 32 + l31;
                float d2 = fmaxf(sqi + sqj[ni] - 2.f * acc[mi][ni][r], 0.f);
                float tv = (offdiag || j > i) ? (-2.0f * d2) : NEG_INF_SENT;
                acc[mi][ni][r] = tv;
                m = fmaxf(m, tv);
            }
        }
    }
    float s = 0.f;
#pragma unroll
    for (int mi = 0; mi < 2; ++mi)
#pragma unroll
        for (int ni = 0; ni < 2; ++ni)
#pragma unroll
            for (int r = 0; r < 16; ++r)
                s += __expf(acc[mi][ni][r] - m);

#pragma unroll
    for (int off = 32; off > 0; off >>= 1) {
        float m2 = __shfl_down(m, off, 64);
        float s2 = __shfl_down(s, off, 64);
        lse_merge(m, s, m2, s2);
    }
    __shared__ float rm[4], rs[4];
    if (lane == 0) { rm[w] = m; rs[w] = s; }
    __syncthreads();
    if (tid == 0) {
#pragma unroll
        for (int v = 1; v < 4; ++v) lse_merge(rm[0], rs[0], rm[v], rs[v]);
        bm[p] = rm[0];
        bs[p] = rs[0];
    }
}

__global__ __launch_bounds__(256) void finalize_kernel(const float* __restrict__ bm,
                                                       const float* __restrict__ bs,
                                                       int nblocks,
                                                       float* __restrict__ out) {
    const int tid = threadIdx.x;
    float m = NEG_INF_SENT, s = 0.f;
    for (int b = tid; b < nblocks; b += 256) lse_merge(m, s, bm[b], bs[b]);
#pragma unroll
    for (int off = 32; off > 0; off >>= 1) {
        float m2 = __shfl_down(m, off, 64);
        float s2 = __shfl_down(s, off, 64);
        lse_merge(m, s, m2, s2);
    }
    __shared__ float rm[4], rs[4];
    if ((tid & 63) == 0) { rm[tid >> 6] = m; rs[tid >> 6] = s; }
    __syncthreads();
    if (tid == 0) {
#pragma unroll
        for (int v = 1; v < 4; ++v) lse_merge(rm[0], rs[0], rm[v], rs[v]);
        const float log_num_pairs = 17.3285362f;  // log(8192*8191/2)
        out[0] = rm[0] + logf(rs[0]) - log_num_pairs;
    }
}

extern "C" void kernel_launch(void* const* d_in, const int* in_sizes, int n_in,
                              void* d_out, int out_size, void* d_ws, size_t ws_size,
                              hipStream_t stream) {
    const float* x = (const float*)d_in[0];
    float* out = (float*)d_out;

    const size_t xb_bytes = (size_t)N * D / 2;   // 2 MB fp4 (swizzled)
    unsigned char* xb = (unsigned char*)d_ws;
    float* sq = (float*)((char*)d_ws + xb_bytes);
    float* bm = sq + N;
    float* bs = bm + NT;

    cast_rowsq_kernel<<<N / 16, 256, 0, stream>>>(x, xb, sq);
    pair_mfma_kernel<<<NT, 256, 0, stream>>>(xb, sq, bm, bs);
    finalize_kernel<<<1, 256, 0, stream>>>(bm, bs, NT, out);
}